// Round 1
// baseline (67.663 us; speedup 1.0000x reference)
//
#include <hip/hip_runtime.h>

#define NPTS 2048
#define NBATCH 4
#define TI 16          // i's per block
#define SJ 16          // j-slices (threads per i)
#define EPSF 1e-5f

__global__ __launch_bounds__(256) void spring_kernel(
    const float* __restrict__ X,
    const float* __restrict__ Kp,
    const float* __restrict__ Bp,
    float* __restrict__ out)
{
    __shared__ float xs[NPTS], ys[NPTS], zs[NPTS];

    const int tid = threadIdx.x;
    const int blocksPerBatch = NPTS / TI;              // 128
    const int b = blockIdx.x / blocksPerBatch;
    const int i_base = (blockIdx.x % blocksPerBatch) * TI;
    const float* Xb = X + b * (NPTS * 3);

    // Stage this batch's coords into LDS as SoA (conflict-free strided reads later)
    for (int e = tid; e < NPTS * 3; e += 256) {
        float v = Xb[e];
        int n = e / 3;
        int c = e - n * 3;
        if (c == 0)      xs[n] = v;
        else if (c == 1) ys[n] = v;
        else             zs[n] = v;
    }
    __syncthreads();

    const float K  = Kp[0];
    const float Bc = Bp[0];
    const float C  = K * (Bc + EPSF);   // s = K*(d-B)/(d+eps) == K - C/(d+eps)

    const int il = tid >> 4;    // 0..15 : which i this thread works on
    const int js = tid & 15;    // 0..15 : j-slice
    const int i  = i_base + il;

    const float xi = xs[i], yi = ys[i], zi = zs[i];

    float ax = 0.f, ay = 0.f, az = 0.f;
    #pragma unroll 8
    for (int j = js; j < NPTS; j += SJ) {
        float dx = xi - xs[j];
        float dy = yi - ys[j];
        float dz = zi - zs[j];
        float sq = dx*dx + dy*dy + dz*dz;
        // diagonal (sq==0): delta==0 so contribution is 0 for any finite s -> branchless
        float dist = __builtin_amdgcn_sqrtf(sq);
        float r = __builtin_amdgcn_rcpf(dist + EPSF);
        float s = fmaf(-C, r, K);            // K - C/(dist+eps)
        ax = fmaf(dx, s, ax);
        ay = fmaf(dy, s, ay);
        az = fmaf(dz, s, az);
    }

    // reduce 16 partials per i (lanes for one i are consecutive -> width-16 shuffle)
    for (int d = 8; d > 0; d >>= 1) {
        ax += __shfl_down(ax, d, 16);
        ay += __shfl_down(ay, d, 16);
        az += __shfl_down(az, d, 16);
    }

    if (js == 0) {
        float* o = out + (b * NPTS + i) * 3;
        o[0] = xi + ax;
        o[1] = yi + ay;
        o[2] = zi + az;
    }
}

extern "C" void kernel_launch(void* const* d_in, const int* in_sizes, int n_in,
                              void* d_out, int out_size, void* d_ws, size_t ws_size,
                              hipStream_t stream) {
    const float* X  = (const float*)d_in[0];
    const float* Kp = (const float*)d_in[1];
    const float* Bp = (const float*)d_in[2];
    float* out = (float*)d_out;

    dim3 grid(NBATCH * (NPTS / TI));   // 512 blocks
    dim3 block(256);
    spring_kernel<<<grid, block, 0, stream>>>(X, Kp, Bp, out);
}

// Round 2
// 66.995 us; speedup vs baseline: 1.0100x; 1.0100x over previous
//
#include <hip/hip_runtime.h>

#define NPTS 2048
#define EPSF 1e-5f

__global__ __launch_bounds__(256) void spring_kernel(
    const float* __restrict__ X,
    const float* __restrict__ Kp,
    const float* __restrict__ Bp,
    float* __restrict__ out)
{
    __shared__ __align__(16) float xs[NPTS];
    __shared__ __align__(16) float ys[NPTS];
    __shared__ __align__(16) float zs[NPTS];

    const int tid    = threadIdx.x;
    const int b      = blockIdx.x >> 7;            // / 128 blocks-per-batch
    const int i_base = (blockIdx.x & 127) << 4;    // * 16 i's per block
    const float* Xb  = X + b * (NPTS * 3);

    // Stage batch coords into LDS as SoA (coalesced global reads)
    for (int e = tid; e < NPTS * 3; e += 256) {
        float v = Xb[e];
        int n = e / 3;
        int c = e - n * 3;
        if (c == 0)      xs[n] = v;
        else if (c == 1) ys[n] = v;
        else             zs[n] = v;
    }
    __syncthreads();

    const float K  = Kp[0];
    const float KB = K * Bp[0];

    const int il = tid >> 4;     // 0..15 : which i
    const int js = tid & 15;     // 0..15 : j-slice
    const int i  = i_base + il;

    const float xi = xs[i], yi = ys[i], zi = zs[i];

    const float4* xs4 = (const float4*)xs;
    const float4* ys4 = (const float4*)ys;
    const float4* zs4 = (const float4*)zs;

    float ax = 0.f, ay = 0.f, az = 0.f;

    // 512 float4's total; each iter every js-slice consumes one -> 32 iters
    #pragma unroll 4
    for (int t = 0; t < NPTS / 4 / 16; ++t) {
        const int idx = t * 16 + js;               // banks (idx*4+c)%32: 2-way, free
        float4 jx = xs4[idx];
        float4 jy = ys4[idx];
        float4 jz = zs4[idx];

        #define PAIR(cx, cy, cz)                                   \
        {                                                          \
            float dx = xi - (cx), dy = yi - (cy), dz = zi - (cz);  \
            float sq = fmaf(dx, dx, fmaf(dy, dy, dz * dz));        \
            sq = fmaxf(sq, 1e-30f);  /* keep diagonal finite */    \
            float r = __builtin_amdgcn_rsqf(sq);                   \
            float s = fmaf(-KB, r, K);   /* K*(d-B)/d */           \
            ax = fmaf(dx, s, ax);                                  \
            ay = fmaf(dy, s, ay);                                  \
            az = fmaf(dz, s, az);                                  \
        }
        PAIR(jx.x, jy.x, jz.x)
        PAIR(jx.y, jy.y, jz.y)
        PAIR(jx.z, jy.z, jz.z)
        PAIR(jx.w, jy.w, jz.w)
        #undef PAIR
    }

    // reduce the 16 j-slice partials per i (lanes for one i are consecutive)
    for (int d = 8; d > 0; d >>= 1) {
        ax += __shfl_down(ax, d, 16);
        ay += __shfl_down(ay, d, 16);
        az += __shfl_down(az, d, 16);
    }

    if (js == 0) {
        float* o = out + (b * NPTS + i) * 3;
        o[0] = xi + ax;
        o[1] = yi + ay;
        o[2] = zi + az;
    }
}

extern "C" void kernel_launch(void* const* d_in, const int* in_sizes, int n_in,
                              void* d_out, int out_size, void* d_ws, size_t ws_size,
                              hipStream_t stream) {
    const float* X  = (const float*)d_in[0];
    const float* Kp = (const float*)d_in[1];
    const float* Bp = (const float*)d_in[2];
    float* out = (float*)d_out;

    dim3 grid(4 * (NPTS / 16));   // 512 blocks
    dim3 block(256);
    spring_kernel<<<grid, block, 0, stream>>>(X, Kp, Bp, out);
}

// Round 3
// 65.687 us; speedup vs baseline: 1.0301x; 1.0199x over previous
//
#include <hip/hip_runtime.h>

#define NPTS 2048

__global__ __launch_bounds__(256) void spring_kernel(
    const float* __restrict__ X,
    const float* __restrict__ Kp,
    const float* __restrict__ Bp,
    float* __restrict__ out)
{
    __shared__ __align__(16) float xs[NPTS];
    __shared__ __align__(16) float ys[NPTS];
    __shared__ __align__(16) float zs[NPTS];

    const int tid    = threadIdx.x;
    const int b      = blockIdx.x >> 7;            // 128 blocks per batch
    const int i_base = (blockIdx.x & 127) << 4;    // 16 i's per block
    const float* Xb  = X + b * (NPTS * 3);

    // Stage batch coords into LDS as SoA (coalesced global reads)
    for (int e = tid; e < NPTS * 3; e += 256) {
        float v = Xb[e];
        int n = e / 3;
        int c = e - n * 3;
        if (c == 0)      xs[n] = v;
        else if (c == 1) ys[n] = v;
        else             zs[n] = v;
    }
    __syncthreads();

    const float K  = Kp[0];
    const float KB = K * Bp[0];

    // One wave per 4 i's; all 64 lanes slice the j-range.
    const int wv   = tid >> 6;          // 0..3
    const int lane = tid & 63;
    const int i0   = i_base + wv * 4;

    float xi[4], yi[4], zi[4];
    float ax[4] = {0.f,0.f,0.f,0.f};
    float ay[4] = {0.f,0.f,0.f,0.f};
    float az[4] = {0.f,0.f,0.f,0.f};
    #pragma unroll
    for (int q = 0; q < 4; ++q) {
        xi[q] = xs[i0 + q]; yi[q] = ys[i0 + q]; zi[q] = zs[i0 + q];
    }

    const float4* xs4 = (const float4*)xs;
    const float4* ys4 = (const float4*)ys;
    const float4* zs4 = (const float4*)zs;

    // 512 float4s / 64 lanes = 8 iters; each iter: 3 ds_read_b128 -> 16 pairs
    #pragma unroll 2
    for (int t = 0; t < NPTS / 4 / 64; ++t) {
        const int idx = t * 64 + lane;
        float4 jx = xs4[idx];
        float4 jy = ys4[idx];
        float4 jz = zs4[idx];
        const float jxa[4] = {jx.x, jx.y, jx.z, jx.w};
        const float jya[4] = {jy.x, jy.y, jy.z, jy.w};
        const float jza[4] = {jz.x, jz.y, jz.z, jz.w};

        #pragma unroll
        for (int c = 0; c < 4; ++c) {
            #pragma unroll
            for (int q = 0; q < 4; ++q) {
                float dx = xi[q] - jxa[c];
                float dy = yi[q] - jya[c];
                float dz = zi[q] - jza[c];
                float sq = fmaf(dx, dx, fmaf(dy, dy, dz * dz));
                sq = fmaxf(sq, 1e-30f);               // diagonal stays finite
                float r = __builtin_amdgcn_rsqf(sq);
                float s = fmaf(-KB, r, K);            // K*(d-B)/d
                ax[q] = fmaf(dx, s, ax[q]);
                ay[q] = fmaf(dy, s, ay[q]);
                az[q] = fmaf(dz, s, az[q]);
            }
        }
    }

    // Full-wave reduction (64 lanes) for each of the 4 i's
    #pragma unroll
    for (int q = 0; q < 4; ++q) {
        #pragma unroll
        for (int d = 32; d > 0; d >>= 1) {
            ax[q] += __shfl_down(ax[q], d, 64);
            ay[q] += __shfl_down(ay[q], d, 64);
            az[q] += __shfl_down(az[q], d, 64);
        }
    }

    if (lane == 0) {
        #pragma unroll
        for (int q = 0; q < 4; ++q) {
            float* o = out + (b * NPTS + i0 + q) * 3;
            o[0] = xi[q] + ax[q];
            o[1] = yi[q] + ay[q];
            o[2] = zi[q] + az[q];
        }
    }
}

extern "C" void kernel_launch(void* const* d_in, const int* in_sizes, int n_in,
                              void* d_out, int out_size, void* d_ws, size_t ws_size,
                              hipStream_t stream) {
    const float* X  = (const float*)d_in[0];
    const float* Kp = (const float*)d_in[1];
    const float* Bp = (const float*)d_in[2];
    float* out = (float*)d_out;

    dim3 grid(4 * (NPTS / 16));   // 512 blocks
    dim3 block(256);
    spring_kernel<<<grid, block, 0, stream>>>(X, Kp, Bp, out);
}